// Round 3
// 125.811 us; speedup vs baseline: 1.1594x; 1.1594x over previous
//
#include <hip/hip_runtime.h>
#include <hip/hip_bf16.h>
#include <stdint.h>

// Problem constants (fixed by the reference)
#define N_B   16384   // batch
#define D_DIM 1024    // input dim
#define K_K   512     // mixture components
#define L_DIM 128     // latent dim
#define H_DIM 64      // phi hidden
#define SX    1032    // x_bf LDS row stride in shorts (1024 + 8 pad; balanced b128 reads)

typedef __attribute__((ext_vector_type(8))) short short8;   // 8 bf16 = 4 VGPRs (MFMA A/B frag)
typedef __attribute__((ext_vector_type(4))) float f32x4;    // MFMA C/D frag

__device__ __forceinline__ unsigned short f2bf(float f) {   // fp32 -> bf16 RNE (scalar)
    union { float f; unsigned int u; } c; c.f = f;
    unsigned int u = c.u;
    unsigned int r = (u + 0x7FFFu + ((u >> 16) & 1u)) >> 16;
    return (unsigned short)r;
}

__device__ __forceinline__ unsigned int pk2(float a, float b) {  // 2x fp32 -> packed bf16x2
    __hip_bfloat162 t = __float22bfloat162_rn(make_float2(a, b));
    union { __hip_bfloat162 h; unsigned int u; } c; c.h = t;
    return c.u;
}

// ---------------- kernel 1: prep ----------------
// 256 blocks x 256 threads (was 64 blocks: 1 wave/SIMD on a quarter of the chip,
// latency-bound on serial L2 loads). Per block: 2 components (h = relu(z@W1+b1)
// -> bf16, phi2[k] = ||h@W2+b2||^2 exact fp32) + 1/256th of W2 -> bf16.
// Accumulation orders are bit-identical to the original 64-block version.
__global__ __launch_bounds__(256) void prep_kernel(
    const float* __restrict__ z, const float* __restrict__ W1,
    const float* __restrict__ b1, const float* __restrict__ W2,
    const float* __restrict__ b2, unsigned short* __restrict__ W2bf,
    unsigned short* __restrict__ h_bf, float* __restrict__ phi2) {
    __shared__ float zsh[2][L_DIM];     // 1 KB
    __shared__ float hsh[2][H_DIM];     // 512 B
    __shared__ float redp[4][2];
    const int tid = threadIdx.x;
    const int k0 = blockIdx.x * 2;

    // --- W2 -> bf16: 256 blocks x 64 float4 = 16384 float4 = all of W2
    if (tid < 64) {
        int i = blockIdx.x * 64 + tid;
        float4 v = ((const float4*)W2)[i];
        uint2 o = make_uint2(pk2(v.x, v.y), pk2(v.z, v.w));
        *(uint2*)(W2bf + i * 4) = o;
    }
    // --- stage z rows for this block's 2 components (2 x 128 = 256 floats)
    zsh[tid >> 7][tid & 127] = z[k0 * L_DIM + tid];
    __syncthreads();
    // --- h = relu(z@W1+b1): thread (kk = tid>>6, j = tid&63), full 128-dot
    if (tid < 128) {
        const int j = tid & 63, kk = tid >> 6;
        float s = b1[j];
#pragma unroll 8
        for (int l = 0; l < L_DIM; ++l)
            s += zsh[kk][l] * W1[l * H_DIM + j];
        float h = fmaxf(s, 0.0f);
        hsh[kk][j] = h;
        h_bf[(k0 + kk) * H_DIM + j] = f2bf(h);
    }
    __syncthreads();
    // --- phi2[k] = ||h@W2 + b2||^2, exact fp32; thread owns cols d = c*256+tid
    float a0[4], a1[4];
#pragma unroll
    for (int c = 0; c < 4; ++c) {
        float bb = b2[c * 256 + tid];
        a0[c] = bb; a1[c] = bb;
    }
#pragma unroll 8
    for (int j = 0; j < H_DIM; ++j) {
        float h0 = hsh[0][j], h1 = hsh[1][j];
#pragma unroll
        for (int c = 0; c < 4; ++c) {
            float w = W2[j * D_DIM + c * 256 + tid];
            a0[c] += h0 * w;
            a1[c] += h1 * w;
        }
    }
    float ss0 = 0.f, ss1 = 0.f;
#pragma unroll
    for (int c = 0; c < 4; ++c) { ss0 += a0[c] * a0[c]; ss1 += a1[c] * a1[c]; }
    const int lane = tid & 63, wv = tid >> 6;
#pragma unroll
    for (int o = 1; o < 64; o <<= 1) {
        ss0 += __shfl_xor(ss0, o, 64);
        ss1 += __shfl_xor(ss1, o, 64);
    }
    if (lane == 0) { redp[wv][0] = ss0; redp[wv][1] = ss1; }
    __syncthreads();
    if (tid < 2) phi2[k0 + tid] = redp[0][tid] + redp[1][tid] + redp[2][tid] + redp[3][tid];
}

// ---------------- main kernel: per block = one 32-row batch tile ----------------
// 512 blocks x 256 threads, 66 KB LDS -> 2 blocks/CU (8 waves; launch_bounds(256,2)
// allows up to 256 VGPRs, so the deep load pipeline below can't cost occupancy).
// Staging: wave wv owns rows [wv*8, wv*8+8); ALL 32 float4 loads are issued
// before any consume -> one latency exposure, 2x the in-flight bytes vs the
// previous 2x16 batching (8 waves x 512 B = 4 KB/CU in flight).
// Stage 1: u[:, wv*16:+16] = x @ W2^T with a ring-8 register pipeline on the
// L2-hot W2 fragments. Stage 2: S = h @ u^T (512x32) + fused exp / component-sum
// / log / mean.
__global__ __launch_bounds__(256, 2) void main_kernel(
    const float* __restrict__ x, const unsigned short* __restrict__ W2bf,
    const unsigned short* __restrict__ h_bf, const float* __restrict__ phi2,
    const float* __restrict__ b2, float* __restrict__ out) {
    __shared__ __align__(16) unsigned short x_bf[32 * SX];      // 66 KB bf16 x tile
    __shared__ __align__(16) unsigned short u_tile[32 * 72];    // 4.5 KB, stride 72
    __shared__ float phi2s[K_K];                                // 2 KB
    __shared__ float x2s[32], xb2s[32];                         // 256 B
    __shared__ float red[4][32];                                // 512 B

    const int tid = threadIdx.x;
    const int wv  = tid >> 6;      // wave 0..3
    const int l   = tid & 63;      // lane
    const int lm  = l & 15;
    const int q   = l >> 4;        // quad 0..3
    const int n0  = blockIdx.x * 32;

    // b2 slices for the xb2 dot: lane l covers cols sub*256 + l*4 (coalesced)
    float4 b2r[4];
#pragma unroll
    for (int sub = 0; sub < 4; ++sub)
        b2r[sub] = ((const float4*)b2)[sub * 64 + l];

    // phi2 stage (overlaps x loads below)
    phi2s[tid]       = phi2[tid];
    phi2s[256 + tid] = phi2[256 + tid];

    // ---- stage x tile: wave wv owns rows [wv*8, wv*8+8), contiguous 32 KB ----
    // issue all 32 independent float4 loads, THEN consume in issue order
    // (progressive vmcnt waits; exact fp32 x2/xb2 + bf16 pack -> LDS).
    float4 xv[32];
    const float* xbase = x + (size_t)(n0 + wv * 8) * D_DIM + l * 4;
#pragma unroll
    for (int s = 0; s < 8; ++s)
#pragma unroll
        for (int sub = 0; sub < 4; ++sub)
            xv[s * 4 + sub] = *(const float4*)(xbase + (size_t)s * D_DIM + sub * 256);

    float x2a[8], xba[8];
#pragma unroll
    for (int s = 0; s < 8; ++s) {
        float s2 = 0.f, sb = 0.f;
#pragma unroll
        for (int sub = 0; sub < 4; ++sub) {
            float4 v = xv[s * 4 + sub];
            s2 += v.x*v.x + v.y*v.y + v.z*v.z + v.w*v.w;
            sb += v.x*b2r[sub].x + v.y*b2r[sub].y + v.z*b2r[sub].z + v.w*b2r[sub].w;
            uint2 o = make_uint2(pk2(v.x, v.y), pk2(v.z, v.w));
            *(uint2*)&x_bf[(wv * 8 + s) * SX + sub * 256 + l * 4] = o;
        }
        x2a[s] = s2; xba[s] = sb;
    }
    // per-row reduce of x2/xb2 (rows uniquely owned by this wave -> no atomics)
#pragma unroll
    for (int s = 0; s < 8; ++s) {
        float a = x2a[s], b = xba[s];
#pragma unroll
        for (int o = 1; o < 64; o <<= 1) { a += __shfl_xor(a, o, 64); b += __shfl_xor(b, o, 64); }
        if (l == 0) { x2s[wv * 8 + s] = a; xb2s[wv * 8 + s] = b; }
    }
    __syncthreads();

    // ---- stage 1: u[:, wv*16:+16] = x @ W2^T over full K=1024, W2 ring-8 ----
    const unsigned short* w2row = W2bf + (size_t)(wv * 16 + lm) * D_DIM + q * 8;
    short8 wf[8];
#pragma unroll
    for (int p = 0; p < 8; ++p)
        wf[p] = *(const short8*)(w2row + p * 32);
    f32x4 c1[2] = {};
#pragma unroll
    for (int ks = 0; ks < 32; ++ks) {
        const int k0 = ks * 32 + q * 8;
        short8 bw = wf[ks & 7];
        if (ks < 24)
            wf[ks & 7] = *(const short8*)(w2row + (ks + 8) * 32);
        short8 a0 = *(const short8*)&x_bf[lm * SX + k0];          // x rows 0..15
        short8 a1 = *(const short8*)&x_bf[(16 + lm) * SX + k0];   // x rows 16..31
        c1[0] = __builtin_amdgcn_mfma_f32_16x16x32_bf16(a0, bw, c1[0], 0, 0, 0);
        c1[1] = __builtin_amdgcn_mfma_f32_16x16x32_bf16(a1, bw, c1[1], 0, 0, 0);
    }
    // write this wave's 16 u columns (C layout: row = i*16 + q*4 + r, col = wv*16+lm)
#pragma unroll
    for (int i = 0; i < 2; ++i)
#pragma unroll
        for (int r = 0; r < 4; ++r)
            u_tile[(i * 16 + q * 4 + r) * 72 + wv * 16 + lm] = f2bf(c1[i][r]);
    __syncthreads();

    // ---- stage 2: S = h @ u^T, wave wv covers component rows [wv*128, wv*128+128) ----
    f32x4 acc[8][2] = {};
#pragma unroll
    for (int ks = 0; ks < 2; ++ks) {
        const int ko = ks * 32 + q * 8;
        short8 bfr[2];
#pragma unroll
        for (int j = 0; j < 2; ++j)
            bfr[j] = *(const short8*)&u_tile[(j * 16 + lm) * 72 + ko];
#pragma unroll
        for (int i = 0; i < 8; ++i) {
            short8 a = *(const short8*)(h_bf + (size_t)(wv * 128 + i * 16 + lm) * H_DIM + ko);
#pragma unroll
            for (int j = 0; j < 2; ++j)
                acc[i][j] = __builtin_amdgcn_mfma_f32_16x16x32_bf16(a, bfr[j], acc[i][j], 0, 0, 0);
        }
    }
    // ---- epilogue: sq = phi2[m] + (x2[n] - 2*xb2[n]) - 2*S; sum_k exp(-sq) ----
    float xn0 = x2s[lm]      - 2.f * xb2s[lm];
    float xn1 = x2s[16 + lm] - 2.f * xb2s[16 + lm];
    float cs0 = 0.f, cs1 = 0.f;
#pragma unroll
    for (int i = 0; i < 8; ++i) {
#pragma unroll
        for (int r = 0; r < 4; ++r) {
            float p2 = phi2s[wv * 128 + i * 16 + q * 4 + r];
            cs0 += __expf(-(p2 + xn0 - 2.f * acc[i][0][r]));
            cs1 += __expf(-(p2 + xn1 - 2.f * acc[i][1][r]));
        }
    }
    cs0 += __shfl_xor(cs0, 16, 64); cs0 += __shfl_xor(cs0, 32, 64);
    cs1 += __shfl_xor(cs1, 16, 64); cs1 += __shfl_xor(cs1, 32, 64);
    if (l < 16) { red[wv][l] = cs0; red[wv][16 + l] = cs1; }
    __syncthreads();
    // ---- fused final reduction: mean over this block's 32 rows of log(mean_k lik + eps)
    if (tid < 32) {
        float row_lik = red[0][tid] + red[1][tid] + red[2][tid] + red[3][tid];
        float lg = __logf(row_lik * (1.0f / (float)K_K) + 1e-9f);
        lg += __shfl_xor(lg, 1, 64);
        lg += __shfl_xor(lg, 2, 64);
        lg += __shfl_xor(lg, 4, 64);
        lg += __shfl_xor(lg, 8, 64);
        lg += __shfl_xor(lg, 16, 64);
        if (tid == 0) atomicAdd(out, lg * (1.0f / (float)N_B));
    }
}

extern "C" void kernel_launch(void* const* d_in, const int* in_sizes, int n_in,
                              void* d_out, int out_size, void* d_ws, size_t ws_size,
                              hipStream_t stream) {
    const float* x  = (const float*)d_in[0];
    const float* z  = (const float*)d_in[1];
    const float* W1 = (const float*)d_in[2];
    const float* b1 = (const float*)d_in[3];
    const float* W2 = (const float*)d_in[4];
    const float* b2 = (const float*)d_in[5];

    char* ws = (char*)d_ws;
    unsigned short* W2bf = (unsigned short*)(ws);            // 128 KB
    unsigned short* h_bf = (unsigned short*)(ws + 131072);   // 64 KB
    float*          phi2 = (float*)(ws + 196608);            // 2 KB

    hipMemsetAsync(d_out, 0, sizeof(float), stream);
    prep_kernel<<<256, 256, 0, stream>>>(z, W1, b1, W2, b2, W2bf, h_bf, phi2);
    main_kernel<<<N_B / 32, 256, 0, stream>>>(x, W2bf, h_bf, phi2, b2, (float*)d_out);
}